// Round 7
// baseline (355.765 us; speedup 1.0000x reference)
//
#include <hip/hip_runtime.h>
#include <hip/hip_bf16.h>

#define N_NODES 100000
#define N_EDGES 1600000
#define N_FEAT  16
#define HIDDEN  128
#define N_GRAPHS 512
#define CAP     64            // fixed bucket capacity (mean deg 16, P(>63)~1e-14)

typedef unsigned short ushort_t;
typedef short v8s __attribute__((ext_vector_type(8)));   // 8 bf16 (4 VGPRs)
typedef float v4f __attribute__((ext_vector_type(4)));   // MFMA accumulator

__device__ __forceinline__ ushort_t f2bf(float f) {
    __hip_bfloat16 b = __float2bfloat16(f);
    return *(ushort_t*)&b;
}
__device__ __forceinline__ float bf_lo(unsigned u) {
    union { unsigned i; float f; } c; c.i = u << 16; return c.f;
}
__device__ __forceinline__ float bf_hi(unsigned u) {
    union { unsigned i; float f; } c; c.i = u & 0xffff0000u; return c.f;
}

// ---------------- fused count + fixed-stride bucket ----------------

__global__ void k_build(const int* __restrict__ src, const int* __restrict__ dst,
                        int* __restrict__ cnt, int* __restrict__ esrc64) {
    int e = blockIdx.x * 256 + threadIdx.x;
    if (e < N_EDGES) {
        int d = dst[e];
        int p = atomicAdd(&cnt[d], 1);
        if (p < CAP) esrc64[(d << 6) + p] = src[e];
    }
}

// ---------------- dinv ----------------

__global__ void k_dinv(const int* __restrict__ cnt, float* __restrict__ dinv) {
    int i = blockIdx.x * 256 + threadIdx.x;
    if (i < N_NODES) dinv[i] = rsqrtf((float)cnt[i] + 1.0f);
}

// ---------------- x' = x * dinv[node] ----------------

__global__ void k_prescale(const float* __restrict__ x, const float* __restrict__ dinv,
                           float* __restrict__ xs) {
    int i = blockIdx.x * 256 + threadIdx.x;   // over N_NODES*N_FEAT
    xs[i] = x[i] * dinv[i >> 4];
}

// ---------------- fused layer-1: agg(16-dim) + mm1 + relu -> h1' = dinv*relu bf16 ----------------
// 1 wave/node: lanes = 4 edge-groups x 16 feats; gather of prescaled x'.

__global__ __launch_bounds__(256) void k_agg1f(const int* __restrict__ cnt,
                                               const int* __restrict__ esrc64,
                                               const float* __restrict__ dinv,
                                               const float* __restrict__ xs,
                                               const float* __restrict__ W1,
                                               const float* __restrict__ b1,
                                               ushort_t* __restrict__ h1) {
    __shared__ float sw[N_FEAT * HIDDEN];   // 8 KB
    __shared__ float sb[HIDDEN];
    int tid = threadIdx.x;
    for (int i = tid; i < N_FEAT * HIDDEN; i += 256) sw[i] = W1[i];
    if (tid < HIDDEN) sb[tid] = b1[tid];
    __syncthreads();

    int wv = tid >> 6, lane = tid & 63;
    int e = lane >> 4, f = lane & 15;
    int node = blockIdx.x * 4 + wv;
    int deg = cnt[node]; deg = deg > CAP ? CAP : deg;
    float dd = dinv[node];
    int base = node << 6;

    float a = 0.0f;
    int j = e;
    for (; j + 4 < deg; j += 8) {
        int sA = esrc64[base + j];
        int sB = esrc64[base + j + 4];
        a += xs[sA * N_FEAT + f] + xs[sB * N_FEAT + f];
    }
    if (j < deg) {
        int s = esrc64[base + j];
        a += xs[s * N_FEAT + f];
    }
    a += __shfl_xor(a, 16, 64);
    a += __shfl_xor(a, 32, 64);
    a = (a + xs[node * N_FEAT + f]) * dd;   // + self (x' already has one dinv)

    // mm1: lane covers output cols lane and lane+64 (bank-clean)
    float c0 = sb[lane], c1 = sb[lane + 64];
    #pragma unroll
    for (int k = 0; k < N_FEAT; ++k) {
        float ak = __shfl(a, k, 64);        // feature k lives on lane k
        c0 += ak * sw[k * HIDDEN + lane];
        c1 += ak * sw[k * HIDDEN + lane + 64];
    }
    size_t rb = (size_t)node * HIDDEN;
    h1[rb + lane]      = f2bf(dd * fmaxf(c0, 0.0f));   // h1' = dinv[node]*relu
    h1[rb + lane + 64] = f2bf(dd * fmaxf(c1, 0.0f));
}

// ---------------- layer-2 aggregation: aggb = bf16(dd * (h1'[self] + sum h1'[s])) ----------------

__global__ __launch_bounds__(256) void k_agg2(const int* __restrict__ cnt,
                                              const int* __restrict__ esrc64,
                                              const float* __restrict__ dinv,
                                              const ushort_t* __restrict__ h1,
                                              ushort_t* __restrict__ aggb) {
    int tid = threadIdx.x;
    int sub = tid >> 5;      // 0..7 node within block
    int l32 = tid & 31;      // 8-byte lane within node row
    int node = blockIdx.x * 8 + sub;
    const uint2* h = (const uint2*)h1;
    int deg = cnt[node]; deg = deg > CAP ? CAP : deg;
    int base = node << 6;
    float dd = dinv[node];

    uint2 sv = h[node * 32 + l32];
    float a0 = bf_lo(sv.x), a1 = bf_hi(sv.x), a2 = bf_lo(sv.y), a3 = bf_hi(sv.y);

    int j = 0;
    for (; j + 4 <= deg; j += 4) {
        int s0 = esrc64[base + j],     s1 = esrc64[base + j + 1];
        int s2 = esrc64[base + j + 2], s3 = esrc64[base + j + 3];
        uint2 v0 = h[s0 * 32 + l32];
        uint2 v1 = h[s1 * 32 + l32];
        uint2 v2 = h[s2 * 32 + l32];
        uint2 v3 = h[s3 * 32 + l32];
        a0 += bf_lo(v0.x) + bf_lo(v1.x) + bf_lo(v2.x) + bf_lo(v3.x);
        a1 += bf_hi(v0.x) + bf_hi(v1.x) + bf_hi(v2.x) + bf_hi(v3.x);
        a2 += bf_lo(v0.y) + bf_lo(v1.y) + bf_lo(v2.y) + bf_lo(v3.y);
        a3 += bf_hi(v0.y) + bf_hi(v1.y) + bf_hi(v2.y) + bf_hi(v3.y);
    }
    for (; j < deg; ++j) {
        int s = esrc64[base + j];
        uint2 v = h[s * 32 + l32];
        a0 += bf_lo(v.x); a1 += bf_hi(v.x);
        a2 += bf_lo(v.y); a3 += bf_hi(v.y);
    }
    ushort4 r;
    r.x = f2bf(a0 * dd); r.y = f2bf(a1 * dd);
    r.z = f2bf(a2 * dd); r.w = f2bf(a3 * dd);
    ((ushort4*)aggb)[node * 32 + l32] = r;
}

// ---------------- pack W2 -> bf16 MFMA B-fragment order ----------------

__global__ void k_packB(const float* __restrict__ W2, ushort_t* __restrict__ Bp) {
    int idx = blockIdx.x * 256 + threadIdx.x;   // 0..16383
    int j = idx & 7;
    int lane = (idx >> 3) & 63;
    int nt = (idx >> 9) & 7;
    int kt = idx >> 12;
    int k = kt * 32 + (lane >> 4) * 8 + j;
    int n = nt * 16 + (lane & 15);
    Bp[idx] = f2bf(W2[k * HIDDEN + n]);
}

// ---------------- mm2 via MFMA, fused head ----------------

__global__ __launch_bounds__(256) void k_mm2m(const ushort_t* __restrict__ A,
                                              const ushort_t* __restrict__ Bp,
                                              const float* __restrict__ b2,
                                              const float* __restrict__ Wl,
                                              float* __restrict__ snode) {
    __shared__ ushort_t sB[16384];   // 32 KB packed W2
    int tid = threadIdx.x;
    {
        const uint4* s = (const uint4*)Bp;
        uint4* d = (uint4*)sB;
        #pragma unroll
        for (int j = 0; j < 8; ++j) d[tid + 256 * j] = s[tid + 256 * j];
    }
    __syncthreads();

    int wv = tid >> 6, lane = tid & 63;
    int m = lane & 15, quad = lane >> 4;
    int node0 = blockIdx.x * 64 + wv * 16;
    const ushort_t* arow = A + (size_t)(node0 + m) * HIDDEN;

    v4f acc[8];
    #pragma unroll
    for (int nt = 0; nt < 8; ++nt) acc[nt] = (v4f){0.f, 0.f, 0.f, 0.f};

    #pragma unroll
    for (int kt = 0; kt < 4; ++kt) {
        v8s a = *(const v8s*)(arow + kt * 32 + quad * 8);
        #pragma unroll
        for (int nt = 0; nt < 8; ++nt) {
            v8s b = *(const v8s*)(&sB[((kt * 8 + nt) * 64 + lane) * 8]);
            acc[nt] = __builtin_amdgcn_mfma_f32_16x16x32_bf16(a, b, acc[nt], 0, 0, 0);
        }
    }

    float part[4] = {0, 0, 0, 0};
    #pragma unroll
    for (int nt = 0; nt < 8; ++nt) {
        float bb = b2[nt * 16 + m];
        float wl = Wl[nt * 16 + m];
        #pragma unroll
        for (int reg = 0; reg < 4; ++reg)
            part[reg] += fmaxf(acc[nt][reg] + bb, 0.0f) * wl;
    }
    #pragma unroll
    for (int reg = 0; reg < 4; ++reg) {
        float p = part[reg];
        p += __shfl_xor(p, 1, 64);
        p += __shfl_xor(p, 2, 64);
        p += __shfl_xor(p, 4, 64);
        p += __shfl_xor(p, 8, 64);
        int node = node0 + quad * 4 + reg;
        if (m == 0 && node < N_NODES) snode[node] = p;
    }
}

// ---------------- pooling: out[g] = mean(snode over graph g) + bl ----------------

__global__ __launch_bounds__(256) void k_pool(const float* __restrict__ snode,
                                              const int* __restrict__ batch,
                                              const float* __restrict__ bl,
                                              float* __restrict__ out) {
    int g = blockIdx.x;
    int tid = threadIdx.x;
    __shared__ float sred[4];

    int lo = 0, hi = N_NODES;
    while (lo < hi) { int mid = (lo + hi) >> 1; if (batch[mid] < g) lo = mid + 1; else hi = mid; }
    int start = lo;
    hi = N_NODES;
    while (lo < hi) { int mid = (lo + hi) >> 1; if (batch[mid] < g + 1) lo = mid + 1; else hi = mid; }
    int end = lo;

    float acc = 0.0f;
    for (int n = start + tid; n < end; n += 256) acc += snode[n];

    #pragma unroll
    for (int off = 32; off; off >>= 1) acc += __shfl_down(acc, off, 64);
    int wave = tid >> 6, lane = tid & 63;
    if (lane == 0) sred[wave] = acc;
    __syncthreads();
    if (tid == 0) {
        float s = sred[0] + sred[1] + sred[2] + sred[3];
        float cnt = (float)(end - start);
        out[g] = s / fmaxf(cnt, 1.0f) + bl[0];
    }
}

// ---------------- launch ----------------

extern "C" void kernel_launch(void* const* d_in, const int* in_sizes, int n_in,
                              void* d_out, int out_size, void* d_ws, size_t ws_size,
                              hipStream_t stream) {
    const float* x    = (const float*)d_in[0];
    const int*   src  = (const int*)d_in[1];
    const int*   dst  = src + N_EDGES;
    const int*   batch= (const int*)d_in[2];
    const float* W1   = (const float*)d_in[3];
    const float* b1   = (const float*)d_in[4];
    const float* W2   = (const float*)d_in[5];
    const float* b2   = (const float*)d_in[6];
    const float* Wl   = (const float*)d_in[7];
    const float* bl   = (const float*)d_in[8];
    float* out = (float*)d_out;

    const size_t NH = (size_t)N_NODES * HIDDEN;

    ushort_t* h1   = (ushort_t*)d_ws;              // NH bf16 (25.6 MB)
    ushort_t* aggb = h1 + NH;                      // NH bf16 (25.6 MB)
    float* xs      = (float*)(aggb + NH);          // N_NODES*16 fp32 (6.4 MB)
    float* dinv    = xs + (size_t)N_NODES * N_FEAT;// N_NODES
    float* snode   = dinv + N_NODES;               // N_NODES
    int*   cnt     = (int*)(snode + N_NODES);      // N_NODES
    int*   esrc64  = cnt + N_NODES;                // N_NODES*64 (25.6 MB)
    ushort_t* Bp   = (ushort_t*)(esrc64 + (size_t)N_NODES * CAP);  // 16384

    // fused count + bucket (fixed stride), then dinv + prescale
    hipMemsetAsync(cnt, 0, N_NODES * sizeof(int), stream);
    k_build<<<(N_EDGES + 255) / 256, 256, 0, stream>>>(src, dst, cnt, esrc64);
    k_dinv<<<(N_NODES + 255) / 256, 256, 0, stream>>>(cnt, dinv);
    k_prescale<<<(N_NODES * N_FEAT + 255) / 256, 256, 0, stream>>>(x, dinv, xs);
    k_packB<<<64, 256, 0, stream>>>(W2, Bp);

    // layer 1 fused: aggregate(16) + mm1 + relu -> h1' (pre-scaled bf16)
    k_agg1f<<<N_NODES / 4, 256, 0, stream>>>(cnt, esrc64, dinv, xs, W1, b1, h1);

    // layer 2: pure-add bf16 gather aggregate -> bf16, MFMA mm2 + fused head
    k_agg2<<<N_NODES / 8, 256, 0, stream>>>(cnt, esrc64, dinv, h1, aggb);
    k_mm2m<<<(N_NODES + 63) / 64, 256, 0, stream>>>(aggb, Bp, b2, Wl, snode);

    // pool + bias
    k_pool<<<N_GRAPHS, 256, 0, stream>>>(snode, batch, bl, out);
}

// Round 8
// 268.832 us; speedup vs baseline: 1.3234x; 1.3234x over previous
//
#include <hip/hip_runtime.h>
#include <hip/hip_bf16.h>

#define N_NODES 100000
#define N_EDGES 1600000
#define N_FEAT  16
#define HIDDEN  128
#define N_GRAPHS 512
#define CAP     64            // slots per node (mean deg 16, P(>63)~0)
#define NBKT    196           // ceil(100000/512) coarse buckets (dst>>9)
#define CAPB    9216          // edges per bucket cap (mean 8192, +11 sigma)
#define EPB     4000          // edges per k_part block (400 blocks)

typedef unsigned short ushort_t;
typedef short v8s __attribute__((ext_vector_type(8)));   // 8 bf16 (4 VGPRs)
typedef float v4f __attribute__((ext_vector_type(4)));   // MFMA accumulator

__device__ __forceinline__ ushort_t f2bf(float f) {
    __hip_bfloat16 b = __float2bfloat16(f);
    return *(ushort_t*)&b;
}
__device__ __forceinline__ float bf_lo(unsigned u) {
    union { unsigned i; float f; } c; c.i = u << 16; return c.f;
}
__device__ __forceinline__ float bf_hi(unsigned u) {
    union { unsigned i; float f; } c; c.i = u & 0xffff0000u; return c.f;
}

// ---------------- phase 1: coarse partition by dst>>9 ----------------
// Per-block LDS histogram -> one global atomicAdd per (block,bucket) ->
// LDS-ranked scatter of (src,dst) into per-bucket windows.

__global__ __launch_bounds__(256) void k_part(const int* __restrict__ src,
                                              const int* __restrict__ dst,
                                              int* __restrict__ bcnt,
                                              int2* __restrict__ ebuf) {
    __shared__ int h[NBKT];
    __shared__ int base[NBKT];
    __shared__ int r[NBKT];
    int tid = threadIdx.x;
    int e0 = blockIdx.x * EPB;

    for (int i = tid; i < NBKT; i += 256) { h[i] = 0; r[i] = 0; }
    __syncthreads();

    // pass A: local histogram
    for (int i = tid; i < EPB; i += 256)
        atomicAdd(&h[dst[e0 + i] >> 9], 1);
    __syncthreads();

    // pass B: claim global windows (196 hot words -> cheap)
    for (int i = tid; i < NBKT; i += 256)
        base[i] = atomicAdd(&bcnt[i], h[i]);
    __syncthreads();

    // pass C: ranked scatter
    for (int i = tid; i < EPB; i += 256) {
        int s = src[e0 + i], d = dst[e0 + i];
        int b = d >> 9;
        int pos = base[b] + atomicAdd(&r[b], 1);
        if (pos < CAPB) ebuf[b * CAPB + pos] = (int2){s, d};
    }
}

// ---------------- phase 2: per-bucket LDS ranking -> esrc64 + cnt + dinv ----------------

__global__ __launch_bounds__(256) void k_fill(const int* __restrict__ bcnt,
                                              const int2* __restrict__ ebuf,
                                              int* __restrict__ esrc64,
                                              int* __restrict__ cnt,
                                              float* __restrict__ dinv) {
    __shared__ int lcnt[512];
    int tid = threadIdx.x;
    int b = blockIdx.x;
    int node0 = b << 9;

    for (int i = tid; i < 512; i += 256) lcnt[i] = 0;
    __syncthreads();

    int nE = bcnt[b]; nE = nE > CAPB ? CAPB : nE;
    const int2* eb = ebuf + b * CAPB;
    for (int i = tid; i < nE; i += 256) {
        int2 e = eb[i];
        int p = atomicAdd(&lcnt[e.y - node0], 1);
        if (p < CAP) esrc64[(e.y << 6) + p] = e.x;
    }
    __syncthreads();

    for (int i = tid; i < 512; i += 256) {
        int node = node0 + i;
        if (node < N_NODES) {
            int c = lcnt[i];
            cnt[node] = c;
            dinv[node] = rsqrtf((float)c + 1.0f);
        }
    }
}

// ---------------- x' = x * dinv[node] ----------------

__global__ void k_prescale(const float* __restrict__ x, const float* __restrict__ dinv,
                           float* __restrict__ xs) {
    int i = blockIdx.x * 256 + threadIdx.x;   // over N_NODES*N_FEAT
    xs[i] = x[i] * dinv[i >> 4];
}

// ---------------- fused layer-1: agg(16-dim) + mm1 + relu -> h1' = dinv*relu bf16 ----------------

__global__ __launch_bounds__(256) void k_agg1f(const int* __restrict__ cnt,
                                               const int* __restrict__ esrc64,
                                               const float* __restrict__ dinv,
                                               const float* __restrict__ xs,
                                               const float* __restrict__ W1,
                                               const float* __restrict__ b1,
                                               ushort_t* __restrict__ h1) {
    __shared__ float sw[N_FEAT * HIDDEN];   // 8 KB
    __shared__ float sb[HIDDEN];
    int tid = threadIdx.x;
    for (int i = tid; i < N_FEAT * HIDDEN; i += 256) sw[i] = W1[i];
    if (tid < HIDDEN) sb[tid] = b1[tid];
    __syncthreads();

    int wv = tid >> 6, lane = tid & 63;
    int e = lane >> 4, f = lane & 15;
    int node = blockIdx.x * 4 + wv;
    int deg = cnt[node]; deg = deg > CAP ? CAP : deg;
    float dd = dinv[node];
    int base = node << 6;

    float a = 0.0f;
    int j = e;
    for (; j + 4 < deg; j += 8) {
        int sA = esrc64[base + j];
        int sB = esrc64[base + j + 4];
        a += xs[sA * N_FEAT + f] + xs[sB * N_FEAT + f];
    }
    if (j < deg) {
        int s = esrc64[base + j];
        a += xs[s * N_FEAT + f];
    }
    a += __shfl_xor(a, 16, 64);
    a += __shfl_xor(a, 32, 64);
    a = (a + xs[node * N_FEAT + f]) * dd;   // + self (x' already has one dinv)

    float c0 = sb[lane], c1 = sb[lane + 64];
    #pragma unroll
    for (int k = 0; k < N_FEAT; ++k) {
        float ak = __shfl(a, k, 64);        // feature k lives on lane k
        c0 += ak * sw[k * HIDDEN + lane];
        c1 += ak * sw[k * HIDDEN + lane + 64];
    }
    size_t rb = (size_t)node * HIDDEN;
    h1[rb + lane]      = f2bf(dd * fmaxf(c0, 0.0f));   // h1' = dinv[node]*relu
    h1[rb + lane + 64] = f2bf(dd * fmaxf(c1, 0.0f));
}

// ---------------- layer-2 aggregation: aggb = bf16(dd * (h1'[self] + sum h1'[s])) ----------------

__global__ __launch_bounds__(256) void k_agg2(const int* __restrict__ cnt,
                                              const int* __restrict__ esrc64,
                                              const float* __restrict__ dinv,
                                              const ushort_t* __restrict__ h1,
                                              ushort_t* __restrict__ aggb) {
    int tid = threadIdx.x;
    int sub = tid >> 5;      // 0..7 node within block
    int l32 = tid & 31;      // 8-byte lane within node row
    int node = blockIdx.x * 8 + sub;
    const uint2* h = (const uint2*)h1;
    int deg = cnt[node]; deg = deg > CAP ? CAP : deg;
    int base = node << 6;
    float dd = dinv[node];

    uint2 sv = h[node * 32 + l32];
    float a0 = bf_lo(sv.x), a1 = bf_hi(sv.x), a2 = bf_lo(sv.y), a3 = bf_hi(sv.y);

    int j = 0;
    for (; j + 4 <= deg; j += 4) {
        int s0 = esrc64[base + j],     s1 = esrc64[base + j + 1];
        int s2 = esrc64[base + j + 2], s3 = esrc64[base + j + 3];
        uint2 v0 = h[s0 * 32 + l32];
        uint2 v1 = h[s1 * 32 + l32];
        uint2 v2 = h[s2 * 32 + l32];
        uint2 v3 = h[s3 * 32 + l32];
        a0 += bf_lo(v0.x) + bf_lo(v1.x) + bf_lo(v2.x) + bf_lo(v3.x);
        a1 += bf_hi(v0.x) + bf_hi(v1.x) + bf_hi(v2.x) + bf_hi(v3.x);
        a2 += bf_lo(v0.y) + bf_lo(v1.y) + bf_lo(v2.y) + bf_lo(v3.y);
        a3 += bf_hi(v0.y) + bf_hi(v1.y) + bf_hi(v2.y) + bf_hi(v3.y);
    }
    for (; j < deg; ++j) {
        int s = esrc64[base + j];
        uint2 v = h[s * 32 + l32];
        a0 += bf_lo(v.x); a1 += bf_hi(v.x);
        a2 += bf_lo(v.y); a3 += bf_hi(v.y);
    }
    ushort4 r;
    r.x = f2bf(a0 * dd); r.y = f2bf(a1 * dd);
    r.z = f2bf(a2 * dd); r.w = f2bf(a3 * dd);
    ((ushort4*)aggb)[node * 32 + l32] = r;
}

// ---------------- pack W2 -> bf16 MFMA B-fragment order ----------------

__global__ void k_packB(const float* __restrict__ W2, ushort_t* __restrict__ Bp) {
    int idx = blockIdx.x * 256 + threadIdx.x;   // 0..16383
    int j = idx & 7;
    int lane = (idx >> 3) & 63;
    int nt = (idx >> 9) & 7;
    int kt = idx >> 12;
    int k = kt * 32 + (lane >> 4) * 8 + j;
    int n = nt * 16 + (lane & 15);
    Bp[idx] = f2bf(W2[k * HIDDEN + n]);
}

// ---------------- mm2 via MFMA, fused head ----------------

__global__ __launch_bounds__(256) void k_mm2m(const ushort_t* __restrict__ A,
                                              const ushort_t* __restrict__ Bp,
                                              const float* __restrict__ b2,
                                              const float* __restrict__ Wl,
                                              float* __restrict__ snode) {
    __shared__ ushort_t sB[16384];   // 32 KB packed W2
    int tid = threadIdx.x;
    {
        const uint4* s = (const uint4*)Bp;
        uint4* d = (uint4*)sB;
        #pragma unroll
        for (int j = 0; j < 8; ++j) d[tid + 256 * j] = s[tid + 256 * j];
    }
    __syncthreads();

    int wv = tid >> 6, lane = tid & 63;
    int m = lane & 15, quad = lane >> 4;
    int node0 = blockIdx.x * 64 + wv * 16;
    const ushort_t* arow = A + (size_t)(node0 + m) * HIDDEN;

    v4f acc[8];
    #pragma unroll
    for (int nt = 0; nt < 8; ++nt) acc[nt] = (v4f){0.f, 0.f, 0.f, 0.f};

    #pragma unroll
    for (int kt = 0; kt < 4; ++kt) {
        v8s a = *(const v8s*)(arow + kt * 32 + quad * 8);
        #pragma unroll
        for (int nt = 0; nt < 8; ++nt) {
            v8s b = *(const v8s*)(&sB[((kt * 8 + nt) * 64 + lane) * 8]);
            acc[nt] = __builtin_amdgcn_mfma_f32_16x16x32_bf16(a, b, acc[nt], 0, 0, 0);
        }
    }

    float part[4] = {0, 0, 0, 0};
    #pragma unroll
    for (int nt = 0; nt < 8; ++nt) {
        float bb = b2[nt * 16 + m];
        float wl = Wl[nt * 16 + m];
        #pragma unroll
        for (int reg = 0; reg < 4; ++reg)
            part[reg] += fmaxf(acc[nt][reg] + bb, 0.0f) * wl;
    }
    #pragma unroll
    for (int reg = 0; reg < 4; ++reg) {
        float p = part[reg];
        p += __shfl_xor(p, 1, 64);
        p += __shfl_xor(p, 2, 64);
        p += __shfl_xor(p, 4, 64);
        p += __shfl_xor(p, 8, 64);
        int node = node0 + quad * 4 + reg;
        if (m == 0 && node < N_NODES) snode[node] = p;
    }
}

// ---------------- pooling: out[g] = mean(snode over graph g) + bl ----------------

__global__ __launch_bounds__(256) void k_pool(const float* __restrict__ snode,
                                              const int* __restrict__ batch,
                                              const float* __restrict__ bl,
                                              float* __restrict__ out) {
    int g = blockIdx.x;
    int tid = threadIdx.x;
    __shared__ float sred[4];

    int lo = 0, hi = N_NODES;
    while (lo < hi) { int mid = (lo + hi) >> 1; if (batch[mid] < g) lo = mid + 1; else hi = mid; }
    int start = lo;
    hi = N_NODES;
    while (lo < hi) { int mid = (lo + hi) >> 1; if (batch[mid] < g + 1) lo = mid + 1; else hi = mid; }
    int end = lo;

    float acc = 0.0f;
    for (int n = start + tid; n < end; n += 256) acc += snode[n];

    #pragma unroll
    for (int off = 32; off; off >>= 1) acc += __shfl_down(acc, off, 64);
    int wave = tid >> 6, lane = tid & 63;
    if (lane == 0) sred[wave] = acc;
    __syncthreads();
    if (tid == 0) {
        float s = sred[0] + sred[1] + sred[2] + sred[3];
        float cnt = (float)(end - start);
        out[g] = s / fmaxf(cnt, 1.0f) + bl[0];
    }
}

// ---------------- launch ----------------

extern "C" void kernel_launch(void* const* d_in, const int* in_sizes, int n_in,
                              void* d_out, int out_size, void* d_ws, size_t ws_size,
                              hipStream_t stream) {
    const float* x    = (const float*)d_in[0];
    const int*   src  = (const int*)d_in[1];
    const int*   dst  = src + N_EDGES;
    const int*   batch= (const int*)d_in[2];
    const float* W1   = (const float*)d_in[3];
    const float* b1   = (const float*)d_in[4];
    const float* W2   = (const float*)d_in[5];
    const float* b2   = (const float*)d_in[6];
    const float* Wl   = (const float*)d_in[7];
    const float* bl   = (const float*)d_in[8];
    float* out = (float*)d_out;

    const size_t NH = (size_t)N_NODES * HIDDEN;

    ushort_t* h1   = (ushort_t*)d_ws;              // NH bf16 (25.6 MB)
    ushort_t* aggb = h1 + NH;                      // NH bf16 (25.6 MB)
    int2*  ebuf    = (int2*)aggb;                  // NBKT*CAPB int2 (14.5 MB), dead before aggb
    float* xs      = (float*)(aggb + NH);          // N_NODES*16 fp32 (6.4 MB)
    float* dinv    = xs + (size_t)N_NODES * N_FEAT;// N_NODES
    float* snode   = dinv + N_NODES;               // N_NODES
    int*   cnt     = (int*)(snode + N_NODES);      // N_NODES
    int*   esrc64  = cnt + N_NODES;                // N_NODES*64 (25.6 MB)
    int*   bcnt    = esrc64 + (size_t)N_NODES * CAP;  // NBKT
    ushort_t* Bp   = (ushort_t*)(bcnt + NBKT);     // 16384 (32 KB)

    // two-phase build: coarse partition, then per-bucket LDS ranking
    hipMemsetAsync(bcnt, 0, NBKT * sizeof(int), stream);
    k_part<<<N_EDGES / EPB, 256, 0, stream>>>(src, dst, bcnt, ebuf);
    k_fill<<<NBKT, 256, 0, stream>>>(bcnt, ebuf, esrc64, cnt, dinv);

    k_prescale<<<(N_NODES * N_FEAT + 255) / 256, 256, 0, stream>>>(x, dinv, xs);
    k_packB<<<64, 256, 0, stream>>>(W2, Bp);

    // layer 1 fused: aggregate(16) + mm1 + relu -> h1' (pre-scaled bf16)
    k_agg1f<<<N_NODES / 4, 256, 0, stream>>>(cnt, esrc64, dinv, xs, W1, b1, h1);

    // layer 2: pure-add bf16 gather aggregate -> bf16, MFMA mm2 + fused head
    k_agg2<<<N_NODES / 8, 256, 0, stream>>>(cnt, esrc64, dinv, h1, aggb);
    k_mm2m<<<(N_NODES + 63) / 64, 256, 0, stream>>>(aggb, Bp, b2, Wl, snode);

    // pool + bias
    k_pool<<<N_GRAPHS, 256, 0, stream>>>(snode, batch, bl, out);
}